// Round 14
// baseline (565.715 us; speedup 1.0000x reference)
//
#include <hip/hip_runtime.h>
#include <hip/hip_bf16.h>
#include <stdint.h>

// MoE FFN, top-1 routing. x:[4,2048,1024] f32, 8 experts, 1024->4096->1024.
// R14: fence-free persistent fused FFN1+FFN2 work queue. H producer/consumer
//      coherence via sc0 sc1 (system-scope) ops meeting at the shared L3;
//      weights stay L2-cached (no invalidations). FFN1: R9 256x256 body.
//      FFN2: 128x128 K=4096 jobs (~30us) to kill ceil-quantization lumps.

#define D_MODEL 1024
#define D_FF    4096
#define NEXP    8
#define NTOK    8192

typedef __attribute__((ext_vector_type(8))) short bf16x8;
typedef __attribute__((ext_vector_type(8))) unsigned short u16x8;
typedef __attribute__((ext_vector_type(4))) unsigned short u16x4;
typedef __attribute__((ext_vector_type(4))) float f32x4;
typedef __attribute__((ext_vector_type(4))) unsigned int u32x4;

// ---- workspace layout (bytes) ----
#define OFF_META 0u
#define OFF_TOPI 4096u
#define OFF_PERM 36864u
#define OFF_POS  69632u
#define OFF_XG   131072u                     // 8448*1024*2
#define OFF_H    17432576u                   // 8448*4096*2
#define OFF_W1T  86638592u                   // 8*4096*1024*2
#define OFF_W2T  153747456u                  // 8*1024*4096*2

__device__ __forceinline__ unsigned short f2bf(float f) {
  unsigned int u = __builtin_bit_cast(unsigned int, f);
  unsigned int r = (u + 0x7FFFu + ((u >> 16) & 1u)) >> 16;
  return (unsigned short)r;
}

typedef const __attribute__((address_space(1))) unsigned int* gas_u32;
typedef __attribute__((address_space(3))) unsigned int* las_u32;

__device__ __forceinline__ void gload16(const void* g, void* l) {
  __builtin_amdgcn_global_load_lds((gas_u32)g, (las_u32)l, 16, 0, 0);
}

// system-scope (sc0 sc1) ops: bypass the non-coherent per-XCD L2.
__device__ __forceinline__ void store_short_sc(void* p, unsigned int v) {
  asm volatile("global_store_short %0, %1, off sc0 sc1" :: "v"(p), "v"(v) : "memory");
}

// ---------------- gating: one wave per token, fp64 accumulate ----------------
__global__ __launch_bounds__(256) void gate_kernel(const float* __restrict__ x,
    const float* __restrict__ gw, const float* __restrict__ gb,
    const float* __restrict__ eb, int* __restrict__ topi) {
  int wid = threadIdx.x >> 6, lane = threadIdx.x & 63;
  int t = blockIdx.x * 4 + wid;
  const float* xr = x + (size_t)t * D_MODEL;
  double p[NEXP];
#pragma unroll
  for (int e = 0; e < NEXP; ++e) p[e] = 0.0;
#pragma unroll
  for (int j = 0; j < 4; ++j) {
    int c = (lane + j * 64) * 4;
    f32x4 xv = *(const f32x4*)(xr + c);
#pragma unroll
    for (int e = 0; e < NEXP; ++e) {
      f32x4 gv = *(const f32x4*)(gw + e * D_MODEL + c);
#pragma unroll
      for (int q = 0; q < 4; ++q) p[e] += (double)xv[q] * (double)gv[q];
    }
  }
#pragma unroll
  for (int e = 0; e < NEXP; ++e) {
    for (int off = 32; off; off >>= 1) p[e] += __shfl_xor(p[e], off, 64);
  }
  if (lane == 0) {
    double best = -1e300; int bi = 0;
#pragma unroll
    for (int e = 0; e < NEXP; ++e) {
      double v = p[e] + (double)gb[e] + (double)eb[e];
      if (v > best) { best = v; bi = e; }
    }
    topi[t] = bi;
  }
}

// ---- rank kernel: counts/offsets/tile maps (256 & 128)/pos/perm/queue ----
__global__ __launch_bounds__(1024) void rank_kernel(const int* __restrict__ topi,
    int* __restrict__ meta, int* __restrict__ pos, int* __restrict__ perm) {
  __shared__ int hist[NEXP][1024];
  __shared__ int offs_s[NEXP + 1];
  int tid = threadIdx.x;
  int te[8], loc[NEXP], run[NEXP];
#pragma unroll
  for (int e = 0; e < NEXP; ++e) loc[e] = 0;
#pragma unroll
  for (int j = 0; j < 8; ++j) {
    te[j] = topi[tid * 8 + j];
#pragma unroll
    for (int e = 0; e < NEXP; ++e) loc[e] += (te[j] == e) ? 1 : 0;
  }
#pragma unroll
  for (int e = 0; e < NEXP; ++e) { run[e] = loc[e]; hist[e][tid] = run[e]; }
  __syncthreads();
  for (int s = 1; s < 1024; s <<= 1) {
    int v[NEXP];
#pragma unroll
    for (int e = 0; e < NEXP; ++e) v[e] = (tid >= s) ? hist[e][tid - s] : 0;
    __syncthreads();
#pragma unroll
    for (int e = 0; e < NEXP; ++e) { run[e] += v[e]; hist[e][tid] = run[e]; }
    __syncthreads();
  }
  if (tid == 1023) {
    int o = 0;
    for (int e = 0; e < NEXP; ++e) {
      offs_s[e] = o;
      meta[e] = run[e];
      meta[8 + e] = o;
      o += run[e];
    }
    offs_s[NEXP] = o; meta[16] = o;
    int nt = 0, base256[NEXP];
    for (int e = 0; e < NEXP; ++e) {
      base256[e] = nt;
      int n256 = (run[e] + 255) >> 8;
      for (int j = 0; j < n256; ++j) { meta[32 + nt] = e; meta[112 + nt] = j; ++nt; }
    }
    meta[25] = nt;
    int nt1 = 0;
    for (int e = 0; e < NEXP; ++e) {
      int n128 = (run[e] + 127) >> 7;
      for (int j = 0; j < n128; ++j) {
        meta[256 + nt1] = e;
        meta[336 + nt1] = j;
        meta[416 + nt1] = base256[e] + (j >> 1);   // parent 256-tile
        ++nt1;
      }
    }
    meta[26] = nt1;
    meta[160] = 0;                             // queue head
    for (int i = 0; i < 40; ++i) meta[192 + i] = 0;  // done flags
  }
  __syncthreads();
  int base[NEXP];
#pragma unroll
  for (int e = 0; e < NEXP; ++e) base[e] = offs_s[e] + run[e] - loc[e];
#pragma unroll
  for (int j = 0; j < 8; ++j) {
    int tok = tid * 8 + j, pj = 0;
#pragma unroll
    for (int e = 0; e < NEXP; ++e) {
      if (te[j] == e) pj = base[e];
      base[e] += (te[j] == e) ? 1 : 0;
    }
    pos[tok] = pj;
    perm[pj] = tok;
  }
}

// -------- scatter tokens into per-expert contiguous rows, f32 -> bf16 --------
__global__ __launch_bounds__(256) void scatter_kernel(const float* __restrict__ x,
    const int* __restrict__ pos, unsigned short* __restrict__ xg) {
  int t = blockIdx.x;
  int p = pos[t];
  const float* xr = x + (size_t)t * D_MODEL;
  unsigned short* orow = xg + (size_t)p * D_MODEL;
  int c = threadIdx.x * 4;
  f32x4 v = *(const f32x4*)(xr + c);
  u16x4 u;
#pragma unroll
  for (int j = 0; j < 4; ++j) u[j] = f2bf(v[j]);
  *(u16x4*)(orow + c) = u;
}

// ---- merged weight convert+transpose: [E][R][C] f32 -> [E][C][R] bf16 ----
__global__ __launch_bounds__(256) void transconv_all(
    const float* __restrict__ w1, unsigned short* __restrict__ w1t,
    const float* __restrict__ w2, unsigned short* __restrict__ w2t) {
  __shared__ float tile[64][65];
  int id = blockIdx.x;
  const float* src; unsigned short* dst; int R, C, c0, r0;
  if (id < 8192) {
    int e = id >> 10, rem = id & 1023;
    R = 1024; C = 4096;
    c0 = (rem & 63) * 64; r0 = (rem >> 6) * 64;
    src = w1 + (size_t)e * R * C; dst = w1t + (size_t)e * R * C;
  } else {
    int e = (id - 8192) >> 10, rem = (id - 8192) & 1023;
    R = 4096; C = 1024;
    c0 = (rem & 15) * 64; r0 = (rem >> 4) * 64;
    src = w2 + (size_t)e * R * C; dst = w2t + (size_t)e * R * C;
  }
  int tid = threadIdx.x;
  int rr = tid >> 4, cc4 = (tid & 15) * 4;
#pragma unroll
  for (int i = 0; i < 4; ++i) {
    f32x4 v = *(const f32x4*)(src + (size_t)(r0 + rr + i * 16) * C + c0 + cc4);
#pragma unroll
    for (int j = 0; j < 4; ++j) tile[rr + i * 16][cc4 + j] = v[j];
  }
  __syncthreads();
  int cc = tid >> 3, rr8 = (tid & 7) * 8;
#pragma unroll
  for (int i = 0; i < 2; ++i) {
    int c = cc + i * 32;
    u16x8 u;
#pragma unroll
    for (int j = 0; j < 8; ++j) u[j] = f2bf(tile[rr8 + j][c]);
    *(u16x8*)(dst + (size_t)(c0 + c) * R + r0 + rr8) = u;
  }
}

// ------------- fence-free persistent fused FFN1+FFN2 work queue -------------
#define SBAR() { __builtin_amdgcn_sched_barrier(0); __builtin_amdgcn_s_barrier(); __builtin_amdgcn_sched_barrier(0); }
#define WAIT_VM(N) { asm volatile("s_waitcnt vmcnt(" #N ")" ::: "memory"); __builtin_amdgcn_sched_barrier(0); }
#define SCHED0() __builtin_amdgcn_sched_barrier(0)

__global__ __launch_bounds__(512, 1) void moe_fused(
    const unsigned short* __restrict__ XG, const unsigned short* __restrict__ W1T,
    const unsigned short* __restrict__ W2T, const float* __restrict__ B1,
    const float* __restrict__ B2, int* __restrict__ meta,
    const int* __restrict__ perm, unsigned short* __restrict__ H,
    float* __restrict__ Out) {
  __shared__ char lds[131072];
  __shared__ int sj;
  int* qhead = meta + 160;
  int* done  = meta + 192;

  int tid = threadIdx.x;
  int lane = tid & 63, wv = tid >> 6;
  int waveM = wv >> 2, waveN = wv & 3;       // 2M x 4N
  int lr = lane & 15, lg = lane >> 4;

  // FFN1 staging constants (256x256, BK=64)
  const int o0 = tid * 16, o1 = o0 + 8192;
  const int lw0 = o0 >> 7, lw1 = o1 >> 7;
  const int co0 = (o0 & 127) ^ ((lw0 & 7) << 4);
  const int co1 = (o1 & 127) ^ ((lw1 & 7) << 4);
  const int mA0 = (lw0 >> 6) * 128 + (lw0 & 63), mA1 = (lw1 >> 6) * 128 + (lw1 & 63);
  const int nB0 = (lw0 >> 5) * 64 + (lw0 & 31), nB1 = (lw1 >> 5) * 64 + (lw1 & 31);

  for (;;) {
    __syncthreads();                         // drains prev job's vm/lgkm + LDS reads
    if (tid == 0) sj = atomicAdd(qhead, 1);
    __syncthreads();
    int j = sj;
    int ntiles = meta[25], ntiles128 = meta[26];
    int j1 = ntiles * 16, j2 = ntiles128 * 8;
    if (j >= j1 + j2) return;

    if (j < j1) {
      // ============ FFN1: 256x256, K=1024, R9 4-phase body ============
      int t = j >> 4, nb = j & 15;
      int e = meta[32 + t];
      int lm = meta[112 + t];
      int off = meta[8 + e];
      int rowsValid = meta[9 + e] - off - lm * 256;
      int m0 = off + lm * 256;
      const char* aBase = (const char*)(XG + (size_t)m0 * D_MODEL);
      const char* bBase = (const char*)(W1T + ((size_t)e * D_FF + nb * 256) * D_MODEL);
      const int SK = D_MODEL * 2;
      const int NT = D_MODEL / 64;

#define ST_A1(D, R, KT) { \
    char* _d = lds + (D) * 65536 + (R) * 16384; \
    gload16(aBase + (size_t)(mA0 + (R) * 64) * SK + (KT) * 128 + co0, _d + o0); \
    gload16(aBase + (size_t)(mA1 + (R) * 64) * SK + (KT) * 128 + co1, _d + o1); }
#define ST_B1(D, R, KT) { \
    char* _d = lds + (D) * 65536 + 32768 + (R) * 16384; \
    gload16(bBase + (size_t)(nB0 + (R) * 32) * SK + (KT) * 128 + co0, _d + o0); \
    gload16(bBase + (size_t)(nB1 + (R) * 32) * SK + (KT) * 128 + co1, _d + o1); }

      bf16x8 a[4][2], b0[2][2], b1[2][2];
#define LD_A1(D, MH) { \
    const char* _b = lds + (D) * 65536 + (MH) * 16384; \
    _Pragma("unroll") for (int mfi = 0; mfi < 4; ++mfi) \
    _Pragma("unroll") for (int kq = 0; kq < 2; ++kq) { \
      int _o = (waveM * 64 + mfi * 16 + lr) * 128 + kq * 64 + lg * 16; \
      _o ^= ((_o >> 7) & 7) << 4; \
      a[mfi][kq] = *(const bf16x8*)(_b + _o); } }
#define LD_B1(D, NH, BV) { \
    const char* _b = lds + (D) * 65536 + 32768 + (NH) * 16384; \
    _Pragma("unroll") for (int nfi = 0; nfi < 2; ++nfi) \
    _Pragma("unroll") for (int kq = 0; kq < 2; ++kq) { \
      int _o = (waveN * 32 + nfi * 16 + lr) * 128 + kq * 64 + lg * 16; \
      _o ^= ((_o >> 7) & 7) << 4; \
      BV[nfi][kq] = *(const bf16x8*)(_b + _o); } }

      f32x4 acc[8][4];
#pragma unroll
      for (int i = 0; i < 8; ++i)
#pragma unroll
        for (int jq = 0; jq < 4; ++jq) acc[i][jq] = (f32x4){0.f, 0.f, 0.f, 0.f};

#define MM1(MH, NH, BV) { \
    __builtin_amdgcn_s_setprio(1); \
    _Pragma("unroll") for (int mfi = 0; mfi < 4; ++mfi) \
    _Pragma("unroll") for (int nfi = 0; nfi < 2; ++nfi) \
    _Pragma("unroll") for (int kq = 0; kq < 2; ++kq) \
      acc[(MH) * 4 + mfi][(NH) * 2 + nfi] = __builtin_amdgcn_mfma_f32_16x16x32_bf16( \
          a[mfi][kq], BV[nfi][kq], acc[(MH) * 4 + mfi][(NH) * 2 + nfi], 0, 0, 0); \
    __builtin_amdgcn_s_setprio(0); }

      ST_A1(0, 0, 0); ST_B1(0, 1, 0); ST_A1(0, 1, 0); ST_B1(0, 0, 0);
      ST_A1(1, 0, 1); ST_B1(1, 1, 1); ST_A1(1, 1, 1);
      WAIT_VM(6); SBAR();

      for (int T = 0; T < NT; ++T) {
        int d = T & 1, dn = d ^ 1;
        int tp1 = T + 1 < NT ? T + 1 : T;
        int tp2 = T + 2 < NT ? T + 2 : T;
        LD_A1(d, 0); LD_B1(d, 0, b0);
        ST_B1(dn, 0, tp1);
        SBAR();
        MM1(0, 0, b0);
        SBAR();
        LD_B1(d, 1, b1);
        ST_A1(d, 0, tp2);
        SBAR();
        MM1(0, 1, b1);
        SBAR();
        LD_A1(d, 1);
        ST_B1(d, 1, tp2);
        SBAR();
        MM1(1, 1, b1);
        SBAR();
        ST_A1(d, 1, tp2);
        SBAR();
        MM1(1, 0, b0);
        WAIT_VM(6);
        SBAR();
      }
      asm volatile("s_waitcnt vmcnt(0)" ::: "memory");

      int cb = nb * 256 + waveN * 64;
#pragma unroll
      for (int mf = 0; mf < 8; ++mf) {
#pragma unroll
        for (int rg = 0; rg < 4; ++rg) {
          int rowt = waveM * 128 + mf * 16 + lg * 4 + rg;
          if (rowt >= rowsValid) continue;
          size_t ro = (size_t)(m0 + rowt) * D_FF;
#pragma unroll
          for (int nf = 0; nf < 4; ++nf) {
            int col = cb + nf * 16 + lr;
            float v = acc[mf][nf][rg] + B1[e * D_FF + col];
            store_short_sc((void*)(H + ro + col), (unsigned int)f2bf(fmaxf(v, 0.f)));
          }
        }
      }
      __syncthreads();                       // all waves' sc-stores retired
      if (tid == 0)
        __hip_atomic_fetch_add(done + t, 1, __ATOMIC_RELAXED, __HIP_MEMORY_SCOPE_AGENT);
#undef ST_A1
#undef ST_B1
#undef LD_A1
#undef LD_B1
#undef MM1
    } else {
      // ========= FFN2: 128x128, K=4096, 1-phase/K-tile, sc-staged A =========
      int jj = j - j1;
      int nb = jj / ntiles128, t = jj % ntiles128;   // n-outer
      int e = meta[256 + t];
      int lm = meta[336 + t];
      int parent = meta[416 + t];
      if (tid == 0) {
        while (__hip_atomic_load(done + parent, __ATOMIC_RELAXED, __HIP_MEMORY_SCOPE_AGENT) < 16)
          __builtin_amdgcn_s_sleep(8);
      }
      __syncthreads();                       // no fence: H read via sc loads

      int off = meta[8 + e];
      int rowsValid = meta[9 + e] - off - lm * 128;
      int m0 = off + lm * 128;
      const char* aBase = (const char*)(H + (size_t)m0 * D_FF);
      const char* bBase = (const char*)(W2T + ((size_t)e * D_MODEL + nb * 128) * D_FF);
      const int SK = D_FF * 2;
      const int NT = D_FF / 64;

      // LDS per buf (32KB): A[128x128B] at 0, B[128x128B] at 16384. 2 bufs.
      u32x4 areg0, areg1;
      const int ro0 = o0 >> 7, rc0 = o0 & 127;       // thread's two A/B slots
      const int ro1 = o1 >> 7, rc1 = o1 & 127;
      const int sw0 = o0 ^ ((ro0 & 7) << 4);
      const int sw1 = o1 ^ ((ro1 & 7) << 4);
      const int cob0 = rc0 ^ ((ro0 & 7) << 4);
      const int cob1 = rc1 ^ ((ro1 & 7) << 4);

#define LD_AG2(KT) { \
    const char* _p0 = aBase + (size_t)ro0 * SK + (KT) * 128 + rc0; \
    const char* _p1 = aBase + (size_t)ro1 * SK + (KT) * 128 + rc1; \
    asm volatile("global_load_dwordx4 %0, %1, off sc0 sc1" : "=&v"(areg0) : "v"(_p0)); \
    asm volatile("global_load_dwordx4 %0, %1, off sc0 sc1" : "=&v"(areg1) : "v"(_p1)); }
#define WR_A2(D) { \
    *(u32x4*)(lds + (D) * 32768 + sw0) = areg0; \
    *(u32x4*)(lds + (D) * 32768 + sw1) = areg1; }
#define ST_B2(D, KT) { \
    char* _d = lds + (D) * 32768 + 16384; \
    gload16(bBase + (size_t)ro0 * SK + (KT) * 128 + cob0, _d + o0); \
    gload16(bBase + (size_t)ro1 * SK + (KT) * 128 + cob1, _d + o1); }

      bf16x8 a2[4][2], bb[2][2];
#define LD_A2(D) { \
    const char* _b = lds + (D) * 32768; \
    _Pragma("unroll") for (int mfi = 0; mfi < 4; ++mfi) \
    _Pragma("unroll") for (int kq = 0; kq < 2; ++kq) { \
      int _o = (waveM * 64 + mfi * 16 + lr) * 128 + kq * 64 + lg * 16; \
      _o ^= ((_o >> 7) & 7) << 4; \
      a2[mfi][kq] = *(const bf16x8*)(_b + _o); } }
#define LD_B2(D) { \
    const char* _b = lds + (D) * 32768 + 16384; \
    _Pragma("unroll") for (int nfi = 0; nfi < 2; ++nfi) \
    _Pragma("unroll") for (int kq = 0; kq < 2; ++kq) { \
      int _o = (waveN * 32 + nfi * 16 + lr) * 128 + kq * 64 + lg * 16; \
      _o ^= ((_o >> 7) & 7) << 4; \
      bb[nfi][kq] = *(const bf16x8*)(_b + _o); } }

      f32x4 acc2[4][2];
#pragma unroll
      for (int i = 0; i < 4; ++i)
#pragma unroll
        for (int jq = 0; jq < 2; ++jq) acc2[i][jq] = (f32x4){0.f, 0.f, 0.f, 0.f};

#define MM2() { \
    __builtin_amdgcn_s_setprio(1); \
    _Pragma("unroll") for (int mfi = 0; mfi < 4; ++mfi) \
    _Pragma("unroll") for (int nfi = 0; nfi < 2; ++nfi) \
    _Pragma("unroll") for (int kq = 0; kq < 2; ++kq) \
      acc2[mfi][nfi] = __builtin_amdgcn_mfma_f32_16x16x32_bf16( \
          a2[mfi][kq], bb[nfi][kq], acc2[mfi][nfi], 0, 0, 0); \
    __builtin_amdgcn_s_setprio(0); }

      // prologue: tile0 -> buf0
      LD_AG2(0); SCHED0();
      ST_B2(0, 0); SCHED0();
      WAIT_VM(2);
      WR_A2(0);
      WAIT_VM(0);
      SBAR();

      for (int T = 0; T < NT; ++T) {
        int d = T & 1, dn = d ^ 1;
        int tp1 = T + 1 < NT ? T + 1 : T;
        LD_AG2(tp1); SCHED0();               // 2 sc loads (A rows, T+1)
        ST_B2(dn, tp1); SCHED0();            // 2 gloads -> dn.B
        LD_A2(d); LD_B2(d);
        MM2();                               // 16 MFMA
        WAIT_VM(2);                          // A sc-loads done
        WR_A2(dn);                           // ds_write -> dn.A (swizzled)
        WAIT_VM(0);                          // B(T+1) landed
        SBAR();
      }
      asm volatile("s_waitcnt vmcnt(0)" ::: "memory");

      int cb = nb * 128 + waveN * 32;
#pragma unroll
      for (int mf = 0; mf < 4; ++mf) {
#pragma unroll
        for (int rg = 0; rg < 4; ++rg) {
          int rowt = waveM * 64 + mf * 16 + lg * 4 + rg;
          if (rowt >= rowsValid) continue;
          int tok = perm[m0 + rowt];
          size_t ro = (size_t)tok * D_MODEL;
#pragma unroll
          for (int nf = 0; nf < 2; ++nf) {
            int col = cb + nf * 16 + lr;
            Out[ro + col] = acc2[mf][nf][rg] + B2[e * D_MODEL + col];
          }
        }
      }
#undef LD_AG2
#undef WR_A2
#undef ST_B2
#undef LD_A2
#undef LD_B2
#undef MM2
    }
  }
}

extern "C" void kernel_launch(void* const* d_in, const int* in_sizes, int n_in,
                              void* d_out, int out_size, void* d_ws, size_t ws_size,
                              hipStream_t stream) {
  const float* x  = (const float*)d_in[0];
  const float* gw = (const float*)d_in[1];
  const float* gb = (const float*)d_in[2];
  const float* eb = (const float*)d_in[3];
  const float* w1 = (const float*)d_in[4];
  const float* b1 = (const float*)d_in[5];
  const float* w2 = (const float*)d_in[6];
  const float* b2 = (const float*)d_in[7];
  float* out = (float*)d_out;

  char* ws = (char*)d_ws;
  int* meta = (int*)(ws + OFF_META);
  int* topi = (int*)(ws + OFF_TOPI);
  int* perm = (int*)(ws + OFF_PERM);
  int* pos  = (int*)(ws + OFF_POS);
  unsigned short* xg  = (unsigned short*)(ws + OFF_XG);
  unsigned short* h   = (unsigned short*)(ws + OFF_H);
  unsigned short* w1t = (unsigned short*)(ws + OFF_W1T);
  unsigned short* w2t = (unsigned short*)(ws + OFF_W2T);

  hipLaunchKernelGGL(gate_kernel, dim3(NTOK / 4), dim3(256), 0, stream, x, gw, gb, eb, topi);
  hipLaunchKernelGGL(rank_kernel, dim3(1), dim3(1024), 0, stream, topi, meta, pos, perm);
  hipLaunchKernelGGL(scatter_kernel, dim3(NTOK), dim3(256), 0, stream, x, pos, xg);
  hipLaunchKernelGGL(transconv_all, dim3(16384), dim3(256), 0, stream, w1, w1t, w2, w2t);
  hipLaunchKernelGGL(moe_fused, dim3(256), dim3(512), 0, stream,
                     xg, w1t, w2t, b1, b2, meta, perm, h, out);
}

// Round 15
// 300.774 us; speedup vs baseline: 1.8809x; 1.8809x over previous
//
#include <hip/hip_runtime.h>
#include <hip/hip_bf16.h>
#include <stdint.h>

// MoE FFN, top-1 routing. x:[4,2048,1024] f32, 8 experts, 1024->4096->1024.
// R15: R9 GEMM bodies, serial-chain packing: (gate ∥ w1-transconv) in one
//      het kernel; w2-transconv packed as trailing blocks of FFN1's launch
//      (fills the 3rd-round CU quantization hole). No cross-block deps.

#define D_MODEL 1024
#define D_FF    4096
#define NEXP    8
#define NTOK    8192
#define MAXT256 40

typedef __attribute__((ext_vector_type(8))) short bf16x8;
typedef __attribute__((ext_vector_type(8))) unsigned short u16x8;
typedef __attribute__((ext_vector_type(4))) unsigned short u16x4;
typedef __attribute__((ext_vector_type(4))) float f32x4;

// ---- workspace layout (bytes) ----
#define OFF_META 0u
#define OFF_TOPI 4096u
#define OFF_PERM 36864u
#define OFF_POS  69632u
#define OFF_XG   131072u                     // 8448*1024*2
#define OFF_H    17432576u                   // 8448*4096*2
#define OFF_W1T  86638592u                   // 8*4096*1024*2
#define OFF_W2T  153747456u                  // 8*1024*4096*2

__device__ __forceinline__ unsigned short f2bf(float f) {
  unsigned int u = __builtin_bit_cast(unsigned int, f);
  unsigned int r = (u + 0x7FFFu + ((u >> 16) & 1u)) >> 16;
  return (unsigned short)r;
}

typedef const __attribute__((address_space(1))) unsigned int* gas_u32;
typedef __attribute__((address_space(3))) unsigned int* las_u32;

__device__ __forceinline__ void gload16(const void* g, void* l) {
  __builtin_amdgcn_global_load_lds((gas_u32)g, (las_u32)l, 16, 0, 0);
}

__device__ __forceinline__ int xcd_swz(int orig, int nwg) {
  int q = nwg >> 3, r = nwg & 7;
  int xcd = orig & 7, lid = orig >> 3;
  return (xcd < r ? xcd * (q + 1) : r * (q + 1) + (xcd - r) * q) + lid;
}

// ---- het kernel 1: gate (blocks 0..2047) ∥ w1 transconv (blocks 2048..10239)
__global__ __launch_bounds__(256) void het_gate_w1t(const float* __restrict__ x,
    const float* __restrict__ gw, const float* __restrict__ gb,
    const float* __restrict__ eb, int* __restrict__ topi,
    const float* __restrict__ w1, unsigned short* __restrict__ w1t) {
  __shared__ float tile[64][65];
  int bid = blockIdx.x;
  int tid = threadIdx.x;
  if (bid < 2048) {
    // ---------------- gating: one wave per token, fp64 accumulate ----------
    int wid = tid >> 6, lane = tid & 63;
    int t = bid * 4 + wid;
    const float* xr = x + (size_t)t * D_MODEL;
    double p[NEXP];
#pragma unroll
    for (int e = 0; e < NEXP; ++e) p[e] = 0.0;
#pragma unroll
    for (int j = 0; j < 4; ++j) {
      int c = (lane + j * 64) * 4;
      f32x4 xv = *(const f32x4*)(xr + c);
#pragma unroll
      for (int e = 0; e < NEXP; ++e) {
        f32x4 gv = *(const f32x4*)(gw + e * D_MODEL + c);
#pragma unroll
        for (int q = 0; q < 4; ++q) p[e] += (double)xv[q] * (double)gv[q];
      }
    }
#pragma unroll
    for (int e = 0; e < NEXP; ++e) {
      for (int off = 32; off; off >>= 1) p[e] += __shfl_xor(p[e], off, 64);
    }
    if (lane == 0) {
      double best = -1e300; int bi = 0;
#pragma unroll
      for (int e = 0; e < NEXP; ++e) {
        double v = p[e] + (double)gb[e] + (double)eb[e];
        if (v > best) { best = v; bi = e; }
      }
      topi[t] = bi;
    }
  } else {
    // ---- w1 transconv tile: [E][1024][4096] f32 -> [E][4096][1024] bf16 ----
    int id = bid - 2048;                     // [0, 8192)
    int e = id >> 10, rem = id & 1023;       // 64 c-tiles x 16 r-tiles
    const int R = 1024, C = 4096;
    int c0 = (rem & 63) * 64, r0 = (rem >> 6) * 64;
    const float* src = w1 + (size_t)e * R * C;
    unsigned short* dst = w1t + (size_t)e * R * C;
    int rr = tid >> 4, cc4 = (tid & 15) * 4;
#pragma unroll
    for (int i = 0; i < 4; ++i) {
      f32x4 v = *(const f32x4*)(src + (size_t)(r0 + rr + i * 16) * C + c0 + cc4);
#pragma unroll
      for (int j = 0; j < 4; ++j) tile[rr + i * 16][cc4 + j] = v[j];
    }
    __syncthreads();
    int cc = tid >> 3, rr8 = (tid & 7) * 8;
#pragma unroll
    for (int i = 0; i < 2; ++i) {
      int c = cc + i * 32;
      u16x8 u;
#pragma unroll
      for (int j = 0; j < 8; ++j) u[j] = f2bf(tile[rr8 + j][c]);
      *(u16x8*)(dst + (size_t)(c0 + c) * R + r0 + rr8) = u;
    }
  }
}

// ---- rank kernel: 1 block, 1024 threads. counts/offsets/tilemap/pos/perm ----
__global__ __launch_bounds__(1024) void rank_kernel(const int* __restrict__ topi,
    int* __restrict__ meta, int* __restrict__ pos, int* __restrict__ perm) {
  __shared__ int hist[NEXP][1024];
  __shared__ int offs_s[NEXP + 1];
  int tid = threadIdx.x;
  int te[8], loc[NEXP], run[NEXP];
#pragma unroll
  for (int e = 0; e < NEXP; ++e) loc[e] = 0;
#pragma unroll
  for (int j = 0; j < 8; ++j) {
    te[j] = topi[tid * 8 + j];
#pragma unroll
    for (int e = 0; e < NEXP; ++e) loc[e] += (te[j] == e) ? 1 : 0;
  }
#pragma unroll
  for (int e = 0; e < NEXP; ++e) { run[e] = loc[e]; hist[e][tid] = run[e]; }
  __syncthreads();
  for (int s = 1; s < 1024; s <<= 1) {
    int v[NEXP];
#pragma unroll
    for (int e = 0; e < NEXP; ++e) v[e] = (tid >= s) ? hist[e][tid - s] : 0;
    __syncthreads();
#pragma unroll
    for (int e = 0; e < NEXP; ++e) { run[e] += v[e]; hist[e][tid] = run[e]; }
    __syncthreads();
  }
  if (tid == 1023) {
    int o = 0, nt = 0;
    for (int e = 0; e < NEXP; ++e) {
      offs_s[e] = o;
      meta[e] = run[e];
      meta[8 + e] = o;
      o += run[e];
    }
    offs_s[NEXP] = o; meta[16] = o;
    for (int e = 0; e < NEXP; ++e) {
      int ntile = (run[e] + 255) >> 8;        // 256-row m-tiles
      for (int j = 0; j < ntile; ++j) { meta[32 + nt] = e; meta[112 + nt] = j; ++nt; }
    }
    meta[25] = nt;
  }
  __syncthreads();
  int base[NEXP];
#pragma unroll
  for (int e = 0; e < NEXP; ++e) base[e] = offs_s[e] + run[e] - loc[e];
#pragma unroll
  for (int j = 0; j < 8; ++j) {
    int tok = tid * 8 + j, pj = 0;
#pragma unroll
    for (int e = 0; e < NEXP; ++e) {
      if (te[j] == e) pj = base[e];
      base[e] += (te[j] == e) ? 1 : 0;
    }
    pos[tok] = pj;
    perm[pj] = tok;
  }
}

// -------- scatter tokens into per-expert contiguous rows, f32 -> bf16 --------
__global__ __launch_bounds__(256) void scatter_kernel(const float* __restrict__ x,
    const int* __restrict__ pos, unsigned short* __restrict__ xg) {
  int t = blockIdx.x;
  int p = pos[t];
  const float* xr = x + (size_t)t * D_MODEL;
  unsigned short* orow = xg + (size_t)p * D_MODEL;
  int c = threadIdx.x * 4;
  f32x4 v = *(const f32x4*)(xr + c);
  u16x4 u;
#pragma unroll
  for (int j = 0; j < 4; ++j) u[j] = f2bf(v[j]);
  *(u16x4*)(orow + c) = u;
}

// ---------------- shared GEMM schedule macros (R9, proven) ------------------
#define SBAR() { __builtin_amdgcn_sched_barrier(0); __builtin_amdgcn_s_barrier(); __builtin_amdgcn_sched_barrier(0); }
#define WAIT_VM(N) { asm volatile("s_waitcnt vmcnt(" #N ")" ::: "memory"); __builtin_amdgcn_sched_barrier(0); }

// ---- het kernel 2: FFN1 GEMM (blocks 0..639) + w2 transconv (640..4735) ----
// FFN1: 256x256 K=1024, R9 4-phase counted-vmcnt body. Trailing blocks do
// two 64x64 w2 transconv tiles each (512 thr = 2 x 256-thr tiles), filling
// the GEMM's 3rd-round CU holes. FFN2 (next launch) consumes w2t: safe by
// stream order.
__global__ __launch_bounds__(512, 1) void ffn1_het(
    const unsigned short* __restrict__ A, const unsigned short* __restrict__ Bt,
    const float* __restrict__ bias, const int* __restrict__ meta,
    unsigned short* __restrict__ H,
    const float* __restrict__ w2, unsigned short* __restrict__ w2t) {
  __shared__ char lds[131072];
  int bid = blockIdx.x;
  int tid = threadIdx.x;

  if (bid >= MAXT256 * 16) {
    // ---- w2 transconv: [E][4096][1024] f32 -> [E][1024][4096] bf16 ----
    int tsel = tid >> 8, tid2 = tid & 255;
    int tid8 = (bid - MAXT256 * 16) * 2 + tsel;     // [0, 8192)
    int e = tid8 >> 10, rem = tid8 & 1023;          // 16 c-tiles x 64 r-tiles
    const int R = 4096, C = 1024;
    int c0 = (rem & 15) * 64, r0 = (rem >> 4) * 64;
    const float* src = w2 + (size_t)e * R * C;
    unsigned short* dst = w2t + (size_t)e * R * C;
    float (*tile)[65] = (float(*)[65])(lds + tsel * 20480);
    int rr = tid2 >> 4, cc4 = (tid2 & 15) * 4;
#pragma unroll
    for (int i = 0; i < 4; ++i) {
      f32x4 v = *(const f32x4*)(src + (size_t)(r0 + rr + i * 16) * C + c0 + cc4);
#pragma unroll
      for (int j = 0; j < 4; ++j) tile[rr + i * 16][cc4 + j] = v[j];
    }
    __syncthreads();
    int cc = tid2 >> 3, rr8 = (tid2 & 7) * 8;
#pragma unroll
    for (int i = 0; i < 2; ++i) {
      int c = cc + i * 32;
      u16x8 u;
#pragma unroll
      for (int j = 0; j < 8; ++j) u[j] = f2bf(tile[rr8 + j][c]);
      *(u16x8*)(dst + (size_t)(c0 + c) * R + r0 + rr8) = u;
    }
    return;
  }

  // ------------------------- FFN1 GEMM (R9 body) -------------------------
  constexpr int KDIM = D_MODEL, NDIM = D_FF;
  constexpr int NT = KDIM / 64;
  constexpr int SK = KDIM * 2;
  const int NP = NDIM / 256;
  int ntiles = meta[25];
  int nwg = ntiles * NP;
  int orig = bid;
  if (orig >= nwg) return;
  int wid = xcd_swz(orig, nwg);
  int t = wid % ntiles, nb = wid / ntiles;

  int e = meta[32 + t];
  int lm = meta[112 + t];
  int off = meta[8 + e];
  int rowsValid = meta[9 + e] - off - lm * 256;
  int m0 = off + lm * 256;

  int lane = tid & 63, wv = tid >> 6;
  int waveM = wv >> 2, waveN = wv & 3;       // 2M x 4N
  int lr = lane & 15, lg = lane >> 4;

  const char* aBase = (const char*)(A + (size_t)m0 * KDIM);
  const char* bBase = (const char*)(Bt + ((size_t)e * NDIM + nb * 256) * KDIM);

  const int o0 = tid * 16, o1 = o0 + 8192;
  const int lw0 = o0 >> 7, lw1 = o1 >> 7;
  const int co0 = (o0 & 127) ^ ((lw0 & 7) << 4);
  const int co1 = (o1 & 127) ^ ((lw1 & 7) << 4);
  const int mA0 = (lw0 >> 6) * 128 + (lw0 & 63), mA1 = (lw1 >> 6) * 128 + (lw1 & 63);
  const int nB0 = (lw0 >> 5) * 64 + (lw0 & 31), nB1 = (lw1 >> 5) * 64 + (lw1 & 31);

#define ST_A(D, R, KT) { \
    char* _d = lds + (D) * 65536 + (R) * 16384; \
    gload16(aBase + (size_t)(mA0 + (R) * 64) * SK + (KT) * 128 + co0, _d + o0); \
    gload16(aBase + (size_t)(mA1 + (R) * 64) * SK + (KT) * 128 + co1, _d + o1); }
#define ST_B(D, R, KT) { \
    char* _d = lds + (D) * 65536 + 32768 + (R) * 16384; \
    gload16(bBase + (size_t)(nB0 + (R) * 32) * SK + (KT) * 128 + co0, _d + o0); \
    gload16(bBase + (size_t)(nB1 + (R) * 32) * SK + (KT) * 128 + co1, _d + o1); }

  bf16x8 a[4][2], b0[2][2], b1[2][2];
#define LD_A(D, MH) { \
    const char* _b = lds + (D) * 65536 + (MH) * 16384; \
    _Pragma("unroll") for (int mfi = 0; mfi < 4; ++mfi) \
    _Pragma("unroll") for (int kq = 0; kq < 2; ++kq) { \
      int _o = (waveM * 64 + mfi * 16 + lr) * 128 + kq * 64 + lg * 16; \
      _o ^= ((_o >> 7) & 7) << 4; \
      a[mfi][kq] = *(const bf16x8*)(_b + _o); } }
#define LD_B(D, NH, BV) { \
    const char* _b = lds + (D) * 65536 + 32768 + (NH) * 16384; \
    _Pragma("unroll") for (int nfi = 0; nfi < 2; ++nfi) \
    _Pragma("unroll") for (int kq = 0; kq < 2; ++kq) { \
      int _o = (waveN * 32 + nfi * 16 + lr) * 128 + kq * 64 + lg * 16; \
      _o ^= ((_o >> 7) & 7) << 4; \
      BV[nfi][kq] = *(const bf16x8*)(_b + _o); } }

  f32x4 acc[8][4];
#pragma unroll
  for (int i = 0; i < 8; ++i)
#pragma unroll
    for (int j = 0; j < 4; ++j) acc[i][j] = (f32x4){0.f, 0.f, 0.f, 0.f};

#define MM(MH, NH, BV) { \
    __builtin_amdgcn_s_setprio(1); \
    _Pragma("unroll") for (int mfi = 0; mfi < 4; ++mfi) \
    _Pragma("unroll") for (int nfi = 0; nfi < 2; ++nfi) \
    _Pragma("unroll") for (int kq = 0; kq < 2; ++kq) \
      acc[(MH) * 4 + mfi][(NH) * 2 + nfi] = __builtin_amdgcn_mfma_f32_16x16x32_bf16( \
          a[mfi][kq], BV[nfi][kq], acc[(MH) * 4 + mfi][(NH) * 2 + nfi], 0, 0, 0); \
    __builtin_amdgcn_s_setprio(0); }

  {
    int k1 = NT > 1 ? 1 : 0;
    ST_A(0, 0, 0); ST_B(0, 1, 0); ST_A(0, 1, 0); ST_B(0, 0, 0);
    ST_A(1, 0, k1); ST_B(1, 1, k1); ST_A(1, 1, k1);
  }
  WAIT_VM(6); SBAR();

  for (int T = 0; T < NT; ++T) {
    int d = T & 1, dn = d ^ 1;
    int tp1 = T + 1 < NT ? T + 1 : T;
    int tp2 = T + 2 < NT ? T + 2 : T;
    LD_A(d, 0); LD_B(d, 0, b0);
    ST_B(dn, 0, tp1);
    SBAR();
    MM(0, 0, b0);
    SBAR();
    LD_B(d, 1, b1);
    ST_A(d, 0, tp2);
    SBAR();
    MM(0, 1, b1);
    SBAR();
    LD_A(d, 1);
    ST_B(d, 1, tp2);
    SBAR();
    MM(1, 1, b1);
    SBAR();
    ST_A(d, 1, tp2);
    SBAR();
    MM(1, 0, b0);
    WAIT_VM(6);
    SBAR();
  }
  asm volatile("s_waitcnt vmcnt(0)" ::: "memory");

  int cb = nb * 256 + waveN * 64;
#pragma unroll
  for (int mf = 0; mf < 8; ++mf) {
#pragma unroll
    for (int rg = 0; rg < 4; ++rg) {
      int rowt = waveM * 128 + mf * 16 + lg * 4 + rg;
      if (rowt >= rowsValid) continue;
      size_t ro = (size_t)(m0 + rowt) * NDIM;
#pragma unroll
      for (int nf = 0; nf < 4; ++nf) {
        int col = cb + nf * 16 + lr;
        float v = acc[mf][nf][rg] + bias[e * NDIM + col];
        H[ro + col] = f2bf(fmaxf(v, 0.f));
      }
    }
  }
#undef ST_A
#undef ST_B
#undef LD_A
#undef LD_B
#undef MM
}

// ---------------- FFN2: 256x256 grouped GEMM (R9 body, unchanged) -----------
template<int KDIM, int NDIM>
__global__ __launch_bounds__(512, 1) void gemm8_ffn2(
    const unsigned short* __restrict__ A, const unsigned short* __restrict__ Bt,
    const float* __restrict__ bias, const int* __restrict__ meta,
    const int* __restrict__ perm, float* __restrict__ Out) {
  constexpr int NT = KDIM / 64;
  constexpr int SK = KDIM * 2;
  const int NP = NDIM / 256;
  int ntiles = meta[25];
  int nwg = ntiles * NP;
  int orig = blockIdx.x;
  if (orig >= nwg) return;
  int wid = xcd_swz(orig, nwg);
  int t = wid % ntiles, nb = wid / ntiles;

  int e = meta[32 + t];
  int lm = meta[112 + t];
  int off = meta[8 + e];
  int rowsValid = meta[9 + e] - off - lm * 256;
  int m0 = off + lm * 256;

  __shared__ char lds[131072];

  int tid = threadIdx.x;
  int lane = tid & 63, wv = tid >> 6;
  int waveM = wv >> 2, waveN = wv & 3;
  int lr = lane & 15, lg = lane >> 4;

  const char* aBase = (const char*)(A + (size_t)m0 * KDIM);
  const char* bBase = (const char*)(Bt + ((size_t)e * NDIM + nb * 256) * KDIM);

  const int o0 = tid * 16, o1 = o0 + 8192;
  const int lw0 = o0 >> 7, lw1 = o1 >> 7;
  const int co0 = (o0 & 127) ^ ((lw0 & 7) << 4);
  const int co1 = (o1 & 127) ^ ((lw1 & 7) << 4);
  const int mA0 = (lw0 >> 6) * 128 + (lw0 & 63), mA1 = (lw1 >> 6) * 128 + (lw1 & 63);
  const int nB0 = (lw0 >> 5) * 64 + (lw0 & 31), nB1 = (lw1 >> 5) * 64 + (lw1 & 31);

#define ST_A(D, R, KT) { \
    char* _d = lds + (D) * 65536 + (R) * 16384; \
    gload16(aBase + (size_t)(mA0 + (R) * 64) * SK + (KT) * 128 + co0, _d + o0); \
    gload16(aBase + (size_t)(mA1 + (R) * 64) * SK + (KT) * 128 + co1, _d + o1); }
#define ST_B(D, R, KT) { \
    char* _d = lds + (D) * 65536 + 32768 + (R) * 16384; \
    gload16(bBase + (size_t)(nB0 + (R) * 32) * SK + (KT) * 128 + co0, _d + o0); \
    gload16(bBase + (size_t)(nB1 + (R) * 32) * SK + (KT) * 128 + co1, _d + o1); }

  bf16x8 a[4][2], b0[2][2], b1[2][2];
#define LD_A(D, MH) { \
    const char* _b = lds + (D) * 65536 + (MH) * 16384; \
    _Pragma("unroll") for (int mfi = 0; mfi < 4; ++mfi) \
    _Pragma("unroll") for (int kq = 0; kq < 2; ++kq) { \
      int _o = (waveM * 64 + mfi * 16 + lr) * 128 + kq * 64 + lg * 16; \
      _o ^= ((_o >> 7) & 7) << 4; \
      a[mfi][kq] = *(const bf16x8*)(_b + _o); } }
#define LD_B(D, NH, BV) { \
    const char* _b = lds + (D) * 65536 + 32768 + (NH) * 16384; \
    _Pragma("unroll") for (int nfi = 0; nfi < 2; ++nfi) \
    _Pragma("unroll") for (int kq = 0; kq < 2; ++kq) { \
      int _o = (waveN * 32 + nfi * 16 + lr) * 128 + kq * 64 + lg * 16; \
      _o ^= ((_o >> 7) & 7) << 4; \
      BV[nfi][kq] = *(const bf16x8*)(_b + _o); } }

  f32x4 acc[8][4];
#pragma unroll
  for (int i = 0; i < 8; ++i)
#pragma unroll
    for (int j = 0; j < 4; ++j) acc[i][j] = (f32x4){0.f, 0.f, 0.f, 0.f};

#define MM(MH, NH, BV) { \
    __builtin_amdgcn_s_setprio(1); \
    _Pragma("unroll") for (int mfi = 0; mfi < 4; ++mfi) \
    _Pragma("unroll") for (int nfi = 0; nfi < 2; ++nfi) \
    _Pragma("unroll") for (int kq = 0; kq < 2; ++kq) \
      acc[(MH) * 4 + mfi][(NH) * 2 + nfi] = __builtin_amdgcn_mfma_f32_16x16x32_bf16( \
          a[mfi][kq], BV[nfi][kq], acc[(MH) * 4 + mfi][(NH) * 2 + nfi], 0, 0, 0); \
    __builtin_amdgcn_s_setprio(0); }

  {
    int k1 = NT > 1 ? 1 : 0;
    ST_A(0, 0, 0); ST_B(0, 1, 0); ST_A(0, 1, 0); ST_B(0, 0, 0);
    ST_A(1, 0, k1); ST_B(1, 1, k1); ST_A(1, 1, k1);
  }
  WAIT_VM(6); SBAR();

  for (int T = 0; T < NT; ++T) {
    int d = T & 1, dn = d ^ 1;
    int tp1 = T + 1 < NT ? T + 1 : T;
    int tp2 = T + 2 < NT ? T + 2 : T;
    LD_A(d, 0); LD_B(d, 0, b0);
    ST_B(dn, 0, tp1);
    SBAR();
    MM(0, 0, b0);
    SBAR();
    LD_B(d, 1, b1);
    ST_A(d, 0, tp2);
    SBAR();
    MM(0, 1, b1);
    SBAR();
    LD_A(d, 1);
    ST_B(d, 1, tp2);
    SBAR();
    MM(1, 1, b1);
    SBAR();
    ST_A(d, 1, tp2);
    SBAR();
    MM(1, 0, b0);
    WAIT_VM(6);
    SBAR();
  }
  asm volatile("s_waitcnt vmcnt(0)" ::: "memory");

  int cb = nb * 256 + waveN * 64;
#pragma unroll
  for (int mf = 0; mf < 8; ++mf) {
#pragma unroll
    for (int rg = 0; rg < 4; ++rg) {
      int rowt = waveM * 128 + mf * 16 + lg * 4 + rg;
      if (rowt >= rowsValid) continue;
      int tok = perm[m0 + rowt];
      size_t ro = (size_t)tok * NDIM;
#pragma unroll
      for (int nf = 0; nf < 4; ++nf) {
        int col = cb + nf * 16 + lr;
        Out[ro + col] = acc[mf][nf][rg] + bias[e * NDIM + col];
      }
    }
  }
#undef ST_A
#undef ST_B
#undef LD_A
#undef LD_B
#undef MM
}

extern "C" void kernel_launch(void* const* d_in, const int* in_sizes, int n_in,
                              void* d_out, int out_size, void* d_ws, size_t ws_size,
                              hipStream_t stream) {
  const float* x  = (const float*)d_in[0];
  const float* gw = (const float*)d_in[1];
  const float* gb = (const float*)d_in[2];
  const float* eb = (const float*)d_in[3];
  const float* w1 = (const float*)d_in[4];
  const float* b1 = (const float*)d_in[5];
  const float* w2 = (const float*)d_in[6];
  const float* b2 = (const float*)d_in[7];
  float* out = (float*)d_out;

  char* ws = (char*)d_ws;
  int* meta = (int*)(ws + OFF_META);
  int* topi = (int*)(ws + OFF_TOPI);
  int* perm = (int*)(ws + OFF_PERM);
  int* pos  = (int*)(ws + OFF_POS);
  unsigned short* xg  = (unsigned short*)(ws + OFF_XG);
  unsigned short* h   = (unsigned short*)(ws + OFF_H);
  unsigned short* w1t = (unsigned short*)(ws + OFF_W1T);
  unsigned short* w2t = (unsigned short*)(ws + OFF_W2T);

  // gate (2048 blocks) packed with w1 transconv (8192 blocks)
  hipLaunchKernelGGL(het_gate_w1t, dim3(2048 + 8192), dim3(256), 0, stream,
                     x, gw, gb, eb, topi, w1, w1t);
  hipLaunchKernelGGL(rank_kernel, dim3(1), dim3(1024), 0, stream, topi, meta, pos, perm);
  hipLaunchKernelGGL(scatter_kernel, dim3(NTOK), dim3(256), 0, stream, x, pos, xg);
  // FFN1 GEMM (640 blocks) packed with w2 transconv (4096 trailing blocks)
  hipLaunchKernelGGL(ffn1_het, dim3(MAXT256 * 16 + 4096), dim3(512), 0, stream,
                     xg, w1t, b1, meta, h, w2, w2t);
  hipLaunchKernelGGL((gemm8_ffn2<D_FF, D_MODEL>), dim3(MAXT256 * (D_MODEL / 256)), dim3(512), 0, stream,
                     h, w2t, b2, meta, perm, out);
}